// Round 16
// baseline (175.576 us; speedup 1.0000x reference)
//
#include <hip/hip_runtime.h>
#include <hip/hip_bf16.h>
#include <hip/hip_fp16.h>

#define IN_DIM 4096
#define OUT_DIM 4096
#define HAD_SCALE_F 0.08838834764831845f   // 2^-3.5

typedef int   i32x4 __attribute__((ext_vector_type(4)));
typedef float f32x4 __attribute__((ext_vector_type(4)));

// ---------------------------------------------------------------------------
// Kernel A (verified R12/R13): wave/in-register FWHT, 16 elems/thread,
// s_a = rowmax/127, rowsum = s_a*sum(q) (self-consistent decomposition).
// ---------------------------------------------------------------------------
__global__ __launch_bounds__(256)
void had_rows_q(const float* __restrict__ x, int* __restrict__ aq,
                float* __restrict__ rowsum, float* __restrict__ srow)
{
    __shared__ float wmx[4];
    __shared__ int   wqs[4];
    const int tid = threadIdx.x;
    const int wv  = tid >> 6;
    const size_t row = blockIdx.x;
    const float* xr = x + row * IN_DIM + tid * 16;

    float e[16];
    #pragma unroll
    for (int v = 0; v < 4; ++v) {
        const float4 f = ((const float4*)xr)[v];
        e[v*4+0] = f.x; e[v*4+1] = f.y; e[v*4+2] = f.z; e[v*4+3] = f.w;
    }

    #pragma unroll
    for (int s = 1; s < 16; s <<= 1) {
        #pragma unroll
        for (int i = 0; i < 16; ++i) {
            if (!(i & s)) {
                const float u = e[i], w2 = e[i | s];
                e[i]     = u + w2;
                e[i | s] = u - w2;
            }
        }
    }
    #pragma unroll
    for (int m = 1; m <= 4; m <<= 1) {
        const float sgn = (tid & m) ? -1.0f : 1.0f;
        #pragma unroll
        for (int i = 0; i < 16; ++i) {
            const float p = __shfl_xor(e[i], m, 64);
            e[i] = fmaf(sgn, e[i], p);
        }
    }

    float smax = 0.f;
    #pragma unroll
    for (int i = 0; i < 16; ++i) {
        e[i] *= HAD_SCALE_F;
        smax = fmaxf(smax, fabsf(e[i]));
    }
    #pragma unroll
    for (int off = 32; off > 0; off >>= 1)
        smax = fmaxf(smax, __shfl_xor(smax, off, 64));
    if ((tid & 63) == 0) wmx[wv] = smax;
    __syncthreads();
    const float mx  = fmaxf(fmaxf(wmx[0], wmx[1]), fmaxf(wmx[2], wmx[3]));
    const float inv = (mx > 0.f) ? 127.0f / mx : 0.f;
    const float sa  = mx * (1.0f / 127.0f);

    int qsum = 0;
    int pk[4];
    #pragma unroll
    for (int g2 = 0; g2 < 4; ++g2) {
        const int q0 = (int)rintf(e[g2*4+0] * inv);
        const int q1 = (int)rintf(e[g2*4+1] * inv);
        const int q2 = (int)rintf(e[g2*4+2] * inv);
        const int q3 = (int)rintf(e[g2*4+3] * inv);
        qsum += (q0 + q1) + (q2 + q3);
        pk[g2] = (q0 & 0xFF) | ((q1 & 0xFF) << 8) | ((q2 & 0xFF) << 16) | (q3 << 24);
    }
    *(int4*)&aq[row * (IN_DIM / 4) + tid * 4] = make_int4(pk[0], pk[1], pk[2], pk[3]);

    #pragma unroll
    for (int off = 32; off > 0; off >>= 1) qsum += __shfl_xor(qsum, off, 64);
    if ((tid & 63) == 0) wqs[wv] = qsum;
    __syncthreads();
    if (tid == 0) {
        rowsum[row] = sa * (float)((wqs[0] + wqs[1]) + (wqs[2] + wqs[3]));
        srow[row]   = sa;
    }
}

// ---------------------------------------------------------------------------
// Kernel B (verified R15): repack int4 weights into interleaved-nibble chunks.
// packed & 0x0F0F0F0F = kb0 fragment, (packed>>4) & 0x0F0F0F0F = kb1.
// ---------------------------------------------------------------------------
__global__ __launch_bounds__(256)
void unpack_w4i(const int* __restrict__ wp, unsigned char* __restrict__ wf4)
{
    const int gid = blockIdx.x * 256 + threadIdx.x;   // 4096*32*4 = 524288
    const int c   = gid & 3;
    const int kt  = (gid >> 2) & 31;
    const int n   = gid >> 7;
    const int kbase = kt * 128 + c * 16;
    const int* row = wp + (size_t)n * (IN_DIM / 2) + (kbase >> 1);
    const int4 plo0 = *(const int4*)(row);
    const int4 plo1 = *(const int4*)(row + 4);
    const int4 phi0 = *(const int4*)(row + 32);
    const int4 phi1 = *(const int4*)(row + 36);

    #define MKD(lo, hi, lo2, hi2) \
        ( (unsigned)(((lo) & 15) | (((hi) & 15) << 4)) \
        | ((unsigned)((((lo) >> 4) & 15) | ((((hi) >> 4) & 15) << 4)) << 8) \
        | ((unsigned)(((lo2) & 15) | (((hi2) & 15) << 4)) << 16) \
        | ((unsigned)((((lo2) >> 4) & 15) | ((((hi2) >> 4) & 15) << 4)) << 24) )

    uint4 o;
    o.x = MKD(plo0.x, phi0.x, plo0.y, phi0.y);
    o.y = MKD(plo0.z, phi0.z, plo0.w, phi0.w);
    o.z = MKD(plo1.x, phi1.x, plo1.y, phi1.y);
    o.w = MKD(plo1.z, phi1.z, plo1.w, phi1.w);
    #undef MKD
    *(uint4*)(wf4 + (size_t)gid * 16) = o;
}

// ---------------------------------------------------------------------------
// Kernel C (round-16): R15 verbatim + ANTI-PHASE STARTUP STAGGER.
// R15 showed 2 co-resident blocks/CU still give additive LDS+MFMA (45%
// MfmaUtil): both blocks launch simultaneously, run identical periodic code,
// and stay phase-locked (both read LDS together, both MFMA together).
// Fix: one-time startup delay of (wave_slot & 3) * ~650 cyc (s_sleep) —
// co-resident blocks' waves occupy different HW wave slots per SIMD, so the
// blocks start ~half a region period apart and stay anti-phased (identical
// periods preserve the offset). Cost <=2 us once; worst case exact null.
// ---------------------------------------------------------------------------
#define NT 32   // K-regions of 128

#define BAR()        asm volatile("s_barrier" ::: "memory")
#define WAIT_VM(N)   asm volatile("s_waitcnt vmcnt(" #N ")" ::: "memory")
#define WAIT_LGKM0() asm volatile("s_waitcnt lgkmcnt(0)" ::: "memory")

// LDS: A0 @ 0 (16K), A1 @ 16384, B @ 32768 (16K)
#define STAGE_A(buf, kt) do { \
    _Pragma("unroll") for (int R = 0; R < 4; ++R) \
        __builtin_amdgcn_global_load_lds( \
            (const __attribute__((address_space(1))) void*)(sA + ((size_t)R << 17) + (((kt) & 31) << 7)), \
            (__attribute__((address_space(3))) void*)(smem + (buf) * 16384 + R * 4096 + wv * 1024), 16, 0, 0); \
    } while (0)
#define STAGE_B(kt) do { \
    _Pragma("unroll") for (int R = 0; R < 4; ++R) \
        __builtin_amdgcn_global_load_lds( \
            (const __attribute__((address_space(1))) void*)(sB + ((size_t)R << 17) + (((kt) & 31) << 6)), \
            (__attribute__((address_space(3))) void*)(smem + 32768 + R * 4096 + wv * 1024), 16, 0, 0); \
    } while (0)

__global__ __launch_bounds__(256, 2)
void gemm_i8(const signed char* __restrict__ Aq, const unsigned char* __restrict__ Bw4,
             const float* __restrict__ wscale, const float* __restrict__ wadd,
             const float* __restrict__ bias, const float* __restrict__ rowsum,
             const float* __restrict__ srow, float* __restrict__ out)
{
    __shared__ char smem[49152];

    const int tid  = threadIdx.x;
    const int lane = tid & 63;
    const int wv   = tid >> 6;    // wave 0..3 = output col quarter

    // ---- round-16: anti-phase stagger between co-resident blocks ----
    // HW_ID.WAVE_ID (id=4, offset=0, size=4 -> imm 6148): wave slot on SIMD.
    {
        const unsigned slot = __builtin_amdgcn_s_getreg(6148) & 0xFu;
        const int ns = (int)(slot & 3u);
        for (int i = 0; i < ns; ++i) asm volatile("s_sleep 10" ::: "memory");
    }

    // XCD swizzle: 1024 wgs = 8 XCDs x 128
    const int bid = blockIdx.x;
    const int wg  = (bid & 7) * 128 + (bid >> 3);
    const int m0  = (wg >> 4) * 128;   // 64 m-tiles
    const int n0  = (wg & 15) * 256;   // 16 n-tiles

    // ---- A staging (verified pattern): round R = rows R*32..R*32+31 ----
    const int art = tid >> 3;
    const int act = (tid & 7) ^ (art & 7);
    const signed char* sA = Aq + (size_t)(m0 + art) * IN_DIM + act * 16;

    // ---- B staging: 64B rows, round R = rows R*64..R*64+63 ----
    const int brt = tid >> 2;
    const int bct = (tid & 3) ^ (brt & 3);
    const unsigned char* sB = Bw4 + (size_t)(n0 + brt) * 2048 + bct * 16;

    // ---- fragment read offsets ----
    const int l15 = lane & 15, g = lane >> 4, l7 = lane & 7, l3 = lane & 3;
    const int aOff = l15 * 128 + ((g ^ l7) << 4);
    const int bOff = 32768 + (wv * 64 + l15) * 64 + ((g ^ l3) << 4);

    i32x4 afr[4][2], b0[4], b1[4];
    i32x4 acc[8][4] = {};

    // ---- prologue ----
    STAGE_A(0, 0);
    STAGE_B(0);
    WAIT_VM(0);
    BAR();

    #pragma unroll 1
    for (int kt = 0; kt < NT; ++kt) {
        const int cur = kt & 1;

        STAGE_A(cur ^ 1, kt + 1);

        i32x4 bp[4];
        #pragma unroll
        for (int ni = 0; ni < 4; ++ni)
            bp[ni] = *(const i32x4*)(smem + bOff + ni * 1024);
        #pragma unroll
        for (int mi = 0; mi < 4; ++mi) {
            afr[mi][0] = *(const i32x4*)(smem + cur * 16384 + mi * 2048 + aOff);
            afr[mi][1] = *(const i32x4*)(smem + cur * 16384 + mi * 2048 + (aOff ^ 64));
        }
        #pragma unroll
        for (int ni = 0; ni < 4; ++ni) {
            #pragma unroll
            for (int d = 0; d < 4; ++d) {
                b0[ni][d] = bp[ni][d] & 0x0F0F0F0F;
                b1[ni][d] = (int)(((unsigned)bp[ni][d] >> 4) & 0x0F0F0F0F);
            }
        }

        WAIT_LGKM0();
        BAR();
        STAGE_B(kt + 1);

        __builtin_amdgcn_s_setprio(1);
        #pragma unroll
        for (int mi = 0; mi < 4; ++mi)
            #pragma unroll
            for (int ni = 0; ni < 4; ++ni)
                acc[mi][ni] = __builtin_amdgcn_mfma_i32_16x16x64_i8(
                    afr[mi][0], b0[ni], acc[mi][ni], 0, 0, 0);
        #pragma unroll
        for (int mi = 0; mi < 4; ++mi)
            #pragma unroll
            for (int ni = 0; ni < 4; ++ni)
                acc[mi][ni] = __builtin_amdgcn_mfma_i32_16x16x64_i8(
                    afr[mi][1], b1[ni], acc[mi][ni], 0, 0, 0);
        __builtin_amdgcn_s_setprio(0);

        #pragma unroll
        for (int mi = 0; mi < 4; ++mi) {
            afr[mi][0] = *(const i32x4*)(smem + cur * 16384 + (mi + 4) * 2048 + aOff);
            afr[mi][1] = *(const i32x4*)(smem + cur * 16384 + (mi + 4) * 2048 + (aOff ^ 64));
        }
        __builtin_amdgcn_s_setprio(1);
        #pragma unroll
        for (int mi = 0; mi < 4; ++mi)
            #pragma unroll
            for (int ni = 0; ni < 4; ++ni)
                acc[mi + 4][ni] = __builtin_amdgcn_mfma_i32_16x16x64_i8(
                    afr[mi][0], b0[ni], acc[mi + 4][ni], 0, 0, 0);
        #pragma unroll
        for (int mi = 0; mi < 4; ++mi)
            #pragma unroll
            for (int ni = 0; ni < 4; ++ni)
                acc[mi + 4][ni] = __builtin_amdgcn_mfma_i32_16x16x64_i8(
                    afr[mi][1], b1[ni], acc[mi + 4][ni], 0, 0, 0);
        __builtin_amdgcn_s_setprio(0);

        WAIT_VM(0);
        BAR();
    }

    // ---- epilogue: y = srow[m]*wscale[n]*acc + wadd[n]*rowsum[m] + bias[n] ----
    #pragma unroll
    for (int ni = 0; ni < 4; ++ni) {
        const int col = n0 + wv * 64 + ni * 16 + l15;
        const float sc = wscale[col];
        const float ad = wadd[col];
        const float bi = bias[col];
        #pragma unroll
        for (int mi = 0; mi < 8; ++mi) {
            const int row = m0 + mi * 16 + g * 4;
            const float4 rs4 = *(const float4*)&rowsum[row];
            const float4 sr4 = *(const float4*)&srow[row];
            #pragma unroll
            for (int j = 0; j < 4; ++j) {
                const float rs = (j == 0) ? rs4.x : (j == 1) ? rs4.y : (j == 2) ? rs4.z : rs4.w;
                const float sr = (j == 0) ? sr4.x : (j == 1) ? sr4.y : (j == 2) ? sr4.z : sr4.w;
                out[(size_t)(row + j) * OUT_DIM + col] =
                    (float)acc[mi][ni][j] * (sc * sr) + ad * rs + bi;
            }
        }
    }
}

// ---------------------------------------------------------------------------
extern "C" void kernel_launch(void* const* d_in, const int* in_sizes, int n_in,
                              void* d_out, int out_size, void* d_ws, size_t ws_size,
                              hipStream_t stream)
{
    const float* x      = (const float*)d_in[0];
    const int*   wp     = (const int*)d_in[1];
    const float* wscale = (const float*)d_in[2];
    const float* wadd   = (const float*)d_in[3];
    const float* bias   = (const float*)d_in[4];
    float*       out    = (float*)d_out;

    const int M = in_sizes[0] / IN_DIM;   // 8192

    // ws layout: [ wf4 i4 N*K/2 (8MB) | aq i8 M*K | rowsum f32 M | srow f32 M ]
    char* ws = (char*)d_ws;
    unsigned char* wf4 = (unsigned char*)ws;
    const size_t wf_bytes = (size_t)OUT_DIM * IN_DIM / 2;
    int* aq = (int*)(ws + wf_bytes);
    const size_t aq_bytes = (size_t)M * IN_DIM;
    float* rowsum = (float*)(ws + wf_bytes + aq_bytes);
    float* srow   = (float*)(ws + wf_bytes + aq_bytes + (size_t)M * 4);

    unpack_w4i<<<(OUT_DIM * 32 * 4) / 256, 256, 0, stream>>>(wp, wf4);

    had_rows_q<<<M, 256, 0, stream>>>(x, aq, rowsum, srow);

    gemm_i8<<<(M / 128) * (OUT_DIM / 256), 256, 0, stream>>>(
        (const signed char*)aq, wf4, wscale, wadd, bias, rowsum, srow, out);
}